// Round 3
// baseline (652.664 us; speedup 1.0000x reference)
//
#include <hip/hip_runtime.h>
#include <hip/hip_bf16.h>

typedef __bf16 bf16_t;
typedef bf16_t bf16x8 __attribute__((ext_vector_type(8)));
typedef float f32x4 __attribute__((ext_vector_type(4)));

// ---------------------------------------------------------------------------
// K0: Wg1 [k][e] fp32  ->  Wg1T [e][k] bf16  (32x32 LDS tile transpose)
// ---------------------------------------------------------------------------
__global__ void k_wg1t(const float* __restrict__ Wg1, bf16_t* __restrict__ Wg1T) {
    __shared__ float tile[32][33];
    const int k0 = blockIdx.x * 32;
    const int e0 = blockIdx.y * 32;
    const int tx = threadIdx.x;   // 0..31
    const int ty = threadIdx.y;   // 0..7
    #pragma unroll
    for (int i = 0; i < 32; i += 8)
        tile[ty + i][tx] = Wg1[(k0 + ty + i) * 512 + e0 + tx];
    __syncthreads();
    #pragma unroll
    for (int i = 0; i < 32; i += 8)
        Wg1T[(e0 + ty + i) * 512 + k0 + tx] = (bf16_t)tile[tx][ty + i];
}

// ---------------------------------------------------------------------------
// K1: g[b][e] = C_target[b,:] @ Wg2[:,e] + bias[e]   (grid = B x 2 e-halves)
// ---------------------------------------------------------------------------
__global__ __launch_bounds__(256) void k_gate(const float* __restrict__ Ct,
                                              const float* __restrict__ Wg2,
                                              const float* __restrict__ bias,
                                              float* __restrict__ g) {
    __shared__ float q[512];
    const int b = blockIdx.x;
    const int t = threadIdx.x;
    q[t]       = Ct[b * 512 + t];
    q[t + 256] = Ct[b * 512 + t + 256];
    __syncthreads();
    const int e = (blockIdx.y << 8) + t;
    float acc = bias[e];
    #pragma unroll 8
    for (int k = 0; k < 512; ++k)
        acc = fmaf(q[k], Wg2[k * 512 + e], acc);
    g[b * 512 + e] = acc;
}

// ---------------------------------------------------------------------------
// K2: big GEMM + fused relu/w0 reduce.
//   score[r] = sum_e relu( (C[r,:] @ Wg1)[e] + g[b,e] ) * w0[e],  masked.
// RESTRUCTURED K-loop:
//  - B frags come straight from L2 (Wg1T is 512 KB, XCD-L2 resident) via
//    16-B register loads, software-pipelined across k-iters. No B staging,
//    no per-k barriers.
//  - A staged per K-half (64x256 fp32->bf16, XOR-swizzled, 32 KB LDS).
//    Only 4 barriers per block total (vs 32 before).
// ---------------------------------------------------------------------------
__global__ __launch_bounds__(256, 2) void k_score(const float* __restrict__ C,
                                                  const bf16_t* __restrict__ Wg1T,
                                                  const float* __restrict__ g,
                                                  const float* __restrict__ Wg0,
                                                  const int* __restrict__ mask,
                                                  float* __restrict__ score) {
    __shared__ bf16_t As[64 * 256];     // 32 KB, one K-half, swizzled
    __shared__ float  sred[4][64];      //  1 KB

    const int t    = threadIdx.x;
    const int lane = t & 63;
    const int wave = t >> 6;
    const int quad = lane >> 4;
    const int l15  = lane & 15;
    const int row0 = blockIdx.x * 64;   // 2048 blocks
    const int b    = row0 >> 9;
    const int nb   = wave * 128;        // this wave's N base

    f32x4 acc[4][8] = {};               // [mi][ni]

    #pragma unroll
    for (int ph = 0; ph < 2; ++ph) {
        const int k0 = ph << 8;
        __syncthreads();                // previous phase's readers done
        // ---- stage A half: 64 rows x 256 k, fp32 -> bf16, swizzled ----
        #pragma unroll
        for (int i = 0; i < 16; ++i) {
            const int s  = i * 256 + t;          // float4 slot
            const int r  = s >> 6;
            const int c4 = (s & 63) << 2;
            const float4 v = *reinterpret_cast<const float4*>(
                &C[(size_t)(row0 + r) * 512 + k0 + c4]);
            union { bf16_t h[4]; uint2 u; } pk;
            pk.h[0] = (bf16_t)v.x; pk.h[1] = (bf16_t)v.y;
            pk.h[2] = (bf16_t)v.z; pk.h[3] = (bf16_t)v.w;
            const int col = ((((c4 >> 3) ^ (r & 31)) << 3) | (c4 & 7));
            *reinterpret_cast<uint2*>(&As[r * 256 + col]) = pk.u;
        }
        __syncthreads();
        // ---- 8 k-iters, B from L2 registers, pipelined ----
        bf16x8 bcur[8];
        #pragma unroll
        for (int ni = 0; ni < 8; ++ni)
            bcur[ni] = *reinterpret_cast<const bf16x8*>(
                &Wg1T[(size_t)(nb + ni * 16 + l15) * 512 + k0 + quad * 8]);
        #pragma unroll
        for (int ki = 0; ki < 8; ++ki) {
            bf16x8 bnxt[8];
            if (ki < 7) {
                const int kq = k0 + ((ki + 1) << 5) + quad * 8;
                #pragma unroll
                for (int ni = 0; ni < 8; ++ni)
                    bnxt[ni] = *reinterpret_cast<const bf16x8*>(
                        &Wg1T[(size_t)(nb + ni * 16 + l15) * 512 + kq]);
            }
            bf16x8 afr[4];
            #pragma unroll
            for (int mi = 0; mi < 4; ++mi) {
                const int row  = mi * 16 + l15;
                const int gidx = ((ki << 2) | quad) ^ (row & 31);
                afr[mi] = *reinterpret_cast<const bf16x8*>(&As[row * 256 + gidx * 8]);
            }
            #pragma unroll
            for (int mi = 0; mi < 4; ++mi)
                #pragma unroll
                for (int ni = 0; ni < 8; ++ni)
                    acc[mi][ni] = __builtin_amdgcn_mfma_f32_16x16x32_bf16(
                        afr[mi], bcur[ni], acc[mi][ni], 0, 0, 0);
            if (ki < 7) {
                #pragma unroll
                for (int ni = 0; ni < 8; ++ni) bcur[ni] = bnxt[ni];
            }
        }
    }

    // ---- epilogue: relu(u+g)*w0, reduce over n ----
    float rsum[16];
    #pragma unroll
    for (int i = 0; i < 16; ++i) rsum[i] = 0.f;
    #pragma unroll
    for (int ni = 0; ni < 8; ++ni) {
        const int n  = nb + ni * 16 + l15;           // D col = lane&15
        const float gv = g[(b << 9) + n];
        const float w0 = Wg0[n];
        #pragma unroll
        for (int mi = 0; mi < 4; ++mi)
            #pragma unroll
            for (int r = 0; r < 4; ++r) {            // D row = quad*4 + r
                float u = fmaxf(acc[mi][ni][r] + gv, 0.f);
                rsum[mi * 4 + r] = fmaf(u, w0, rsum[mi * 4 + r]);
            }
    }
    #pragma unroll
    for (int i = 0; i < 16; ++i) {
        float v = rsum[i];
        v += __shfl_xor(v, 1);
        v += __shfl_xor(v, 2);
        v += __shfl_xor(v, 4);
        v += __shfl_xor(v, 8);
        rsum[i] = v;
    }
    if (l15 == 0) {
        #pragma unroll
        for (int mi = 0; mi < 4; ++mi)
            #pragma unroll
            for (int r = 0; r < 4; ++r)
                sred[wave][mi * 16 + quad * 4 + r] = rsum[mi * 4 + r];
    }
    __syncthreads();
    if (t < 64) {
        const float sc = sred[0][t] + sred[1][t] + sred[2][t] + sred[3][t];
        const int grow = row0 + t;
        score[grow] = (mask[grow] == 0) ? -1e30f : sc;
    }
}

// ---------------------------------------------------------------------------
// K3: entmax bisection — one wave per batch, grid 256 x 64 thr.
// ---------------------------------------------------------------------------
__global__ __launch_bounds__(64) void k_entmax(const float* __restrict__ score,
                                               const float* __restrict__ alpha,
                                               float* __restrict__ p) {
    const int lane = threadIdx.x;
    const int b    = blockIdx.x;
    const float am1 = alpha[0] - 1.0f;
    const float inv = 1.0f / am1;
    const bool  sq  = fabsf(inv - 2.0f) < 1e-6f;   // alpha==1.5 -> u*u

    const float* sb = score + (b << 9);
    float x[8];
    {
        const float4 v0 = *reinterpret_cast<const float4*>(sb + lane * 8);
        const float4 v1 = *reinterpret_cast<const float4*>(sb + lane * 8 + 4);
        x[0] = v0.x * am1; x[1] = v0.y * am1; x[2] = v0.z * am1; x[3] = v0.w * am1;
        x[4] = v1.x * am1; x[5] = v1.y * am1; x[6] = v1.z * am1; x[7] = v1.w * am1;
    }
    float m = x[0];
    #pragma unroll
    for (int j = 1; j < 8; ++j) m = fmaxf(m, x[j]);
    #pragma unroll
    for (int s = 1; s < 64; s <<= 1) m = fmaxf(m, __shfl_xor(m, s));

    float tau_lo = m - 1.0f;
    float dm = (m - powf(1.0f / 512.0f, am1)) - tau_lo;

    float f_lo;
    {
        float s = 0.f;
        #pragma unroll
        for (int j = 0; j < 8; ++j) {
            const float u = fmaxf(x[j] - tau_lo, 0.f);
            s += sq ? u * u : powf(u, inv);
        }
        #pragma unroll
        for (int sh = 1; sh < 64; sh <<= 1) s += __shfl_xor(s, sh);
        f_lo = s - 1.0f;
    }
    for (int it = 0; it < 50; ++it) {
        dm *= 0.5f;
        const float tau_m = tau_lo + dm;
        float s = 0.f;
        #pragma unroll
        for (int j = 0; j < 8; ++j) {
            const float u = fmaxf(x[j] - tau_m, 0.f);
            s += sq ? u * u : powf(u, inv);
        }
        #pragma unroll
        for (int sh = 1; sh < 64; sh <<= 1) s += __shfl_xor(s, sh);
        if ((s - 1.0f) * f_lo >= 0.f) tau_lo = tau_m;
    }
    const float tau = tau_lo + 0.5f * dm;
    float pj[8];
    float Z = 0.f;
    #pragma unroll
    for (int j = 0; j < 8; ++j) {
        const float u = fmaxf(x[j] - tau, 0.f);
        pj[j] = sq ? u * u : powf(u, inv);
        Z += pj[j];
    }
    #pragma unroll
    for (int sh = 1; sh < 64; sh <<= 1) Z += __shfl_xor(Z, sh);
    const float rz = 1.0f / Z;
    float4 o0, o1;
    o0.x = pj[0] * rz; o0.y = pj[1] * rz; o0.z = pj[2] * rz; o0.w = pj[3] * rz;
    o1.x = pj[4] * rz; o1.y = pj[5] * rz; o1.z = pj[6] * rz; o1.w = pj[7] * rz;
    *reinterpret_cast<float4*>(p + (b << 9) + lane * 8)     = o0;
    *reinterpret_cast<float4*>(p + (b << 9) + lane * 8 + 4) = o1;
}

// ---------------------------------------------------------------------------
// K4: partial attn over l-chunks: part[(b*4+ch)][e] = sum_{l in chunk} p*C
// grid (256, 4). Uniform skip of p==0 rows.
// ---------------------------------------------------------------------------
__global__ __launch_bounds__(256) void k_attn(const float* __restrict__ p,
                                              const float* __restrict__ C,
                                              float* __restrict__ part) {
    __shared__ float pv_s[128];
    const int b  = blockIdx.x;
    const int ch = blockIdx.y;
    const int t  = threadIdx.x;
    const float* Cb = C + (size_t)b * 512 * 512 + (size_t)ch * 128 * 512;
    const float* pb = p + (b << 9) + (ch << 7);
    if (t < 128) pv_s[t] = pb[t];
    __syncthreads();
    float a0 = 0.f, a1 = 0.f;
    for (int l = 0; l < 128; ++l) {
        const float pv = pv_s[l];
        if (pv != 0.f) {                       // uniform branch
            a0 = fmaf(pv, Cb[(size_t)l * 512 + t], a0);
            a1 = fmaf(pv, Cb[(size_t)l * 512 + t + 256], a1);
        }
    }
    float* pp = part + (size_t)((b << 2) + ch) * 512;
    pp[t]       = a0;
    pp[t + 256] = a1;
}

// ---------------------------------------------------------------------------
// K5: out[b][d] += sum_{e in chunk} attn[b][e] * X[b][e][d]
// grid (256, 4 e-chunks), atomicAdd epilogue.
// ---------------------------------------------------------------------------
__global__ __launch_bounds__(256) void k_out(const float* __restrict__ part,
                                             const float* __restrict__ X,
                                             float* __restrict__ out) {
    __shared__ float as_[128];
    const int b  = blockIdx.x;
    const int ec = blockIdx.y;
    const int t  = threadIdx.x;
    if (t < 128) {
        const int e = (ec << 7) + t;
        const float* pp = part + (size_t)(b << 2) * 512;
        as_[t] = pp[e] + pp[512 + e] + pp[1024 + e] + pp[1536 + e];
    }
    __syncthreads();
    const float* Xb = X + (size_t)b * 512 * 256 + (size_t)(ec << 7) * 256;
    float acc = 0.f;
    #pragma unroll 8
    for (int e = 0; e < 128; ++e)
        acc = fmaf(as_[e], Xb[e * 256 + t], acc);
    atomicAdd(&out[(b << 8) + t], acc);
}

// ---------------------------------------------------------------------------
extern "C" void kernel_launch(void* const* d_in, const int* in_sizes, int n_in,
                              void* d_out, int out_size, void* d_ws, size_t ws_size,
                              hipStream_t stream) {
    const float* C_target = (const float*)d_in[0];
    const float* C        = (const float*)d_in[1];
    const float* X        = (const float*)d_in[2];
    const float* alpha    = (const float*)d_in[3];
    const int*   mask     = (const int*)  d_in[4];
    const float* Wg1      = (const float*)d_in[5];
    const float* Wg2      = (const float*)d_in[6];
    const float* Wg0      = (const float*)d_in[7];
    const float* bias     = (const float*)d_in[8];
    float* out = (float*)d_out;

    char* ws = (char*)d_ws;
    bf16_t* wg1t  = (bf16_t*)(ws);                   // 512 KB
    float*  g     = (float*)(ws + (512u << 10));     // 512 KB
    float*  score = (float*)(ws + (1024u << 10));    // 512 KB
    float*  p     = (float*)(ws + (1536u << 10));    // 512 KB
    float*  part  = (float*)(ws + (2048u << 10));    // 2 MB

    k_wg1t  <<<dim3(16, 16), dim3(32, 8), 0, stream>>>(Wg1, wg1t);
    k_gate  <<<dim3(256, 2), 256, 0, stream>>>(C_target, Wg2, bias, g);
    k_score <<<2048, 256, 0, stream>>>(C, wg1t, g, Wg0, mask, score);
    k_entmax<<<256, 64, 0, stream>>>(score, alpha, p);
    k_attn  <<<dim3(256, 4), 256, 0, stream>>>(p, C, part);
    hipMemsetAsync(d_out, 0, (size_t)out_size * sizeof(float), stream);
    k_out   <<<dim3(256, 4), 256, 0, stream>>>(part, X, out);
}

// Round 4
// 621.891 us; speedup vs baseline: 1.0495x; 1.0495x over previous
//
#include <hip/hip_runtime.h>
#include <hip/hip_bf16.h>

typedef __bf16 bf16_t;
typedef bf16_t bf16x8 __attribute__((ext_vector_type(8)));
typedef float f32x4 __attribute__((ext_vector_type(4)));

// ---------------------------------------------------------------------------
// K0: Wg1 [k][e] fp32  ->  Wg1T [e][k] bf16  (32x32 LDS tile transpose)
// ---------------------------------------------------------------------------
__global__ void k_wg1t(const float* __restrict__ Wg1, bf16_t* __restrict__ Wg1T) {
    __shared__ float tile[32][33];
    const int k0 = blockIdx.x * 32;
    const int e0 = blockIdx.y * 32;
    const int tx = threadIdx.x;   // 0..31
    const int ty = threadIdx.y;   // 0..7
    #pragma unroll
    for (int i = 0; i < 32; i += 8)
        tile[ty + i][tx] = Wg1[(k0 + ty + i) * 512 + e0 + tx];
    __syncthreads();
    #pragma unroll
    for (int i = 0; i < 32; i += 8)
        Wg1T[(e0 + ty + i) * 512 + k0 + tx] = (bf16_t)tile[tx][ty + i];
}

// ---------------------------------------------------------------------------
// K1: g[b][e] = C_target[b,:] @ Wg2[:,e] + bias[e]   (grid = B x 2 e-halves)
// ---------------------------------------------------------------------------
__global__ __launch_bounds__(256) void k_gate(const float* __restrict__ Ct,
                                              const float* __restrict__ Wg2,
                                              const float* __restrict__ bias,
                                              float* __restrict__ g) {
    __shared__ float q[512];
    const int b = blockIdx.x;
    const int t = threadIdx.x;
    q[t]       = Ct[b * 512 + t];
    q[t + 256] = Ct[b * 512 + t + 256];
    __syncthreads();
    const int e = (blockIdx.y << 8) + t;
    float acc = bias[e];
    #pragma unroll 8
    for (int k = 0; k < 512; ++k)
        acc = fmaf(q[k], Wg2[k * 512 + e], acc);
    g[b * 512 + e] = acc;
}

// ---------------------------------------------------------------------------
// K2: big GEMM + fused relu/w0 reduce.
//   score[r] = sum_e relu( (C[r,:] @ Wg1)[e] + g[b,e] ) * w0[e],  masked.
// B frags straight from L2 (Wg1T 512 KB, XCD-L2 resident) via 16-B register
// loads. NO manual double-buffer (R3's bnxt[] spilled: WRITE_SIZE 96 MB) —
// the fully-unrolled k-loop lets the compiler pipeline within its VGPR
// budget instead. A staged per K-half (64x256 bf16, XOR-swizzled, 32 KB).
// ---------------------------------------------------------------------------
__global__ __launch_bounds__(256, 2) void k_score(const float* __restrict__ C,
                                                  const bf16_t* __restrict__ Wg1T,
                                                  const float* __restrict__ g,
                                                  const float* __restrict__ Wg0,
                                                  const int* __restrict__ mask,
                                                  float* __restrict__ score) {
    __shared__ bf16_t As[64 * 256];     // 32 KB, one K-half, swizzled
    __shared__ float  sred[4][64];      //  1 KB

    const int t    = threadIdx.x;
    const int lane = t & 63;
    const int wave = t >> 6;
    const int quad = lane >> 4;
    const int l15  = lane & 15;
    const int row0 = blockIdx.x * 64;   // 2048 blocks
    const int b    = row0 >> 9;
    const int nb   = wave * 128;        // this wave's N base

    f32x4 acc[4][8] = {};               // [mi][ni]

    #pragma unroll
    for (int ph = 0; ph < 2; ++ph) {
        const int k0 = ph << 8;
        __syncthreads();                // previous phase's readers done
        // ---- stage A half: 64 rows x 256 k, fp32 -> bf16, swizzled ----
        #pragma unroll
        for (int i = 0; i < 16; ++i) {
            const int s  = i * 256 + t;          // float4 slot
            const int r  = s >> 6;
            const int c4 = (s & 63) << 2;
            const float4 v = *reinterpret_cast<const float4*>(
                &C[(size_t)(row0 + r) * 512 + k0 + c4]);
            union { bf16_t h[4]; uint2 u; } pk;
            pk.h[0] = (bf16_t)v.x; pk.h[1] = (bf16_t)v.y;
            pk.h[2] = (bf16_t)v.z; pk.h[3] = (bf16_t)v.w;
            const int col = ((((c4 >> 3) ^ (r & 31)) << 3) | (c4 & 7));
            *reinterpret_cast<uint2*>(&As[r * 256 + col]) = pk.u;
        }
        __syncthreads();
        // ---- 8 k-iters; B loaded per-iter, compiler pipelines ----
        #pragma unroll
        for (int ki = 0; ki < 8; ++ki) {
            const int kq = k0 + (ki << 5) + quad * 8;
            bf16x8 bcur[8];
            #pragma unroll
            for (int ni = 0; ni < 8; ++ni)
                bcur[ni] = *reinterpret_cast<const bf16x8*>(
                    &Wg1T[(size_t)(nb + ni * 16 + l15) * 512 + kq]);
            bf16x8 afr[4];
            #pragma unroll
            for (int mi = 0; mi < 4; ++mi) {
                const int row  = mi * 16 + l15;
                const int gidx = ((ki << 2) | quad) ^ (row & 31);
                afr[mi] = *reinterpret_cast<const bf16x8*>(&As[row * 256 + gidx * 8]);
            }
            #pragma unroll
            for (int mi = 0; mi < 4; ++mi)
                #pragma unroll
                for (int ni = 0; ni < 8; ++ni)
                    acc[mi][ni] = __builtin_amdgcn_mfma_f32_16x16x32_bf16(
                        afr[mi], bcur[ni], acc[mi][ni], 0, 0, 0);
        }
    }

    // ---- epilogue: relu(u+g)*w0, reduce over n ----
    float rsum[16];
    #pragma unroll
    for (int i = 0; i < 16; ++i) rsum[i] = 0.f;
    #pragma unroll
    for (int ni = 0; ni < 8; ++ni) {
        const int n  = nb + ni * 16 + l15;           // D col = lane&15
        const float gv = g[(b << 9) + n];
        const float w0 = Wg0[n];
        #pragma unroll
        for (int mi = 0; mi < 4; ++mi)
            #pragma unroll
            for (int r = 0; r < 4; ++r) {            // D row = quad*4 + r
                float u = fmaxf(acc[mi][ni][r] + gv, 0.f);
                rsum[mi * 4 + r] = fmaf(u, w0, rsum[mi * 4 + r]);
            }
    }
    #pragma unroll
    for (int i = 0; i < 16; ++i) {
        float v = rsum[i];
        v += __shfl_xor(v, 1);
        v += __shfl_xor(v, 2);
        v += __shfl_xor(v, 4);
        v += __shfl_xor(v, 8);
        rsum[i] = v;
    }
    if (l15 == 0) {
        #pragma unroll
        for (int mi = 0; mi < 4; ++mi)
            #pragma unroll
            for (int r = 0; r < 4; ++r)
                sred[wave][mi * 16 + quad * 4 + r] = rsum[mi * 4 + r];
    }
    __syncthreads();
    if (t < 64) {
        const float sc = sred[0][t] + sred[1][t] + sred[2][t] + sred[3][t];
        const int grow = row0 + t;
        score[grow] = (mask[grow] == 0) ? -1e30f : sc;
    }
}

// ---------------------------------------------------------------------------
// K3: entmax bisection — one wave per batch, grid 256 x 64 thr.
// ---------------------------------------------------------------------------
__global__ __launch_bounds__(64) void k_entmax(const float* __restrict__ score,
                                               const float* __restrict__ alpha,
                                               float* __restrict__ p) {
    const int lane = threadIdx.x;
    const int b    = blockIdx.x;
    const float am1 = alpha[0] - 1.0f;
    const float inv = 1.0f / am1;
    const bool  sq  = fabsf(inv - 2.0f) < 1e-6f;   // alpha==1.5 -> u*u

    const float* sb = score + (b << 9);
    float x[8];
    {
        const float4 v0 = *reinterpret_cast<const float4*>(sb + lane * 8);
        const float4 v1 = *reinterpret_cast<const float4*>(sb + lane * 8 + 4);
        x[0] = v0.x * am1; x[1] = v0.y * am1; x[2] = v0.z * am1; x[3] = v0.w * am1;
        x[4] = v1.x * am1; x[5] = v1.y * am1; x[6] = v1.z * am1; x[7] = v1.w * am1;
    }
    float m = x[0];
    #pragma unroll
    for (int j = 1; j < 8; ++j) m = fmaxf(m, x[j]);
    #pragma unroll
    for (int s = 1; s < 64; s <<= 1) m = fmaxf(m, __shfl_xor(m, s));

    float tau_lo = m - 1.0f;
    float dm = (m - powf(1.0f / 512.0f, am1)) - tau_lo;

    float f_lo;
    {
        float s = 0.f;
        #pragma unroll
        for (int j = 0; j < 8; ++j) {
            const float u = fmaxf(x[j] - tau_lo, 0.f);
            s += sq ? u * u : powf(u, inv);
        }
        #pragma unroll
        for (int sh = 1; sh < 64; sh <<= 1) s += __shfl_xor(s, sh);
        f_lo = s - 1.0f;
    }
    for (int it = 0; it < 50; ++it) {
        dm *= 0.5f;
        const float tau_m = tau_lo + dm;
        float s = 0.f;
        #pragma unroll
        for (int j = 0; j < 8; ++j) {
            const float u = fmaxf(x[j] - tau_m, 0.f);
            s += sq ? u * u : powf(u, inv);
        }
        #pragma unroll
        for (int sh = 1; sh < 64; sh <<= 1) s += __shfl_xor(s, sh);
        if ((s - 1.0f) * f_lo >= 0.f) tau_lo = tau_m;
    }
    const float tau = tau_lo + 0.5f * dm;
    float pj[8];
    float Z = 0.f;
    #pragma unroll
    for (int j = 0; j < 8; ++j) {
        const float u = fmaxf(x[j] - tau, 0.f);
        pj[j] = sq ? u * u : powf(u, inv);
        Z += pj[j];
    }
    #pragma unroll
    for (int sh = 1; sh < 64; sh <<= 1) Z += __shfl_xor(Z, sh);
    const float rz = 1.0f / Z;
    float4 o0, o1;
    o0.x = pj[0] * rz; o0.y = pj[1] * rz; o0.z = pj[2] * rz; o0.w = pj[3] * rz;
    o1.x = pj[4] * rz; o1.y = pj[5] * rz; o1.z = pj[6] * rz; o1.w = pj[7] * rz;
    *reinterpret_cast<float4*>(p + (b << 9) + lane * 8)     = o0;
    *reinterpret_cast<float4*>(p + (b << 9) + lane * 8 + 4) = o1;
}

// ---------------------------------------------------------------------------
// K4: partial attn over l-chunks: part[(b*4+ch)][e] = sum_{l in chunk} p*C.
// Ballot-compacts nonzero p into LDS, then a BRANCH-FREE pipelined loop
// (the old data-dependent branch serialized HBM latency per row).
// ---------------------------------------------------------------------------
__global__ __launch_bounds__(256) void k_attn(const float* __restrict__ p,
                                              const float* __restrict__ C,
                                              float* __restrict__ part) {
    __shared__ float pv_s[128];
    __shared__ int   idx_s[128];
    __shared__ int   cnt_s;
    const int b  = blockIdx.x;
    const int ch = blockIdx.y;
    const int t  = threadIdx.x;
    if (t == 0) cnt_s = 0;
    __syncthreads();
    if (t < 128) {
        const float pv = p[(b << 9) + (ch << 7) + t];
        const unsigned long long mball = __ballot(pv != 0.f);
        const int lane = t & 63;
        int base = 0;
        if (lane == 0) base = atomicAdd(&cnt_s, __popcll(mball));
        base = __shfl(base, 0);
        if (pv != 0.f) {
            const int off = base + __popcll(mball & ((1ull << lane) - 1ull));
            pv_s[off]  = pv;
            idx_s[off] = t;
        }
    }
    __syncthreads();
    const int n = cnt_s;
    const float* Cb = C + (size_t)b * 512 * 512 + (size_t)ch * 128 * 512;
    float a0 = 0.f, a1 = 0.f;
    int i = 0;
    for (; i + 4 <= n; i += 4) {
        float pv0 = pv_s[i],     pv1 = pv_s[i + 1];
        float pv2 = pv_s[i + 2], pv3 = pv_s[i + 3];
        int   l0  = idx_s[i],     l1 = idx_s[i + 1];
        int   l2  = idx_s[i + 2], l3 = idx_s[i + 3];
        const float c00 = Cb[(size_t)l0 * 512 + t], c01 = Cb[(size_t)l0 * 512 + t + 256];
        const float c10 = Cb[(size_t)l1 * 512 + t], c11 = Cb[(size_t)l1 * 512 + t + 256];
        const float c20 = Cb[(size_t)l2 * 512 + t], c21 = Cb[(size_t)l2 * 512 + t + 256];
        const float c30 = Cb[(size_t)l3 * 512 + t], c31 = Cb[(size_t)l3 * 512 + t + 256];
        a0 = fmaf(pv0, c00, a0); a1 = fmaf(pv0, c01, a1);
        a0 = fmaf(pv1, c10, a0); a1 = fmaf(pv1, c11, a1);
        a0 = fmaf(pv2, c20, a0); a1 = fmaf(pv2, c21, a1);
        a0 = fmaf(pv3, c30, a0); a1 = fmaf(pv3, c31, a1);
    }
    for (; i < n; ++i) {
        const float pv = pv_s[i];
        const int   l  = idx_s[i];
        a0 = fmaf(pv, Cb[(size_t)l * 512 + t], a0);
        a1 = fmaf(pv, Cb[(size_t)l * 512 + t + 256], a1);
    }
    float* pp = part + (size_t)((b << 2) + ch) * 512;
    pp[t]       = a0;
    pp[t + 256] = a1;
}

// ---------------------------------------------------------------------------
// K5: out[b][d] += sum_{e in chunk} attn[b][e] * X[b][e][d]
// grid (256, 4 e-chunks), atomicAdd epilogue.
// ---------------------------------------------------------------------------
__global__ __launch_bounds__(256) void k_out(const float* __restrict__ part,
                                             const float* __restrict__ X,
                                             float* __restrict__ out) {
    __shared__ float as_[128];
    const int b  = blockIdx.x;
    const int ec = blockIdx.y;
    const int t  = threadIdx.x;
    if (t < 128) {
        const int e = (ec << 7) + t;
        const float* pp = part + (size_t)(b << 2) * 512;
        as_[t] = pp[e] + pp[512 + e] + pp[1024 + e] + pp[1536 + e];
    }
    __syncthreads();
    const float* Xb = X + (size_t)b * 512 * 256 + (size_t)(ec << 7) * 256;
    float acc = 0.f;
    #pragma unroll 8
    for (int e = 0; e < 128; ++e)
        acc = fmaf(as_[e], Xb[e * 256 + t], acc);
    atomicAdd(&out[(b << 8) + t], acc);
}

// ---------------------------------------------------------------------------
extern "C" void kernel_launch(void* const* d_in, const int* in_sizes, int n_in,
                              void* d_out, int out_size, void* d_ws, size_t ws_size,
                              hipStream_t stream) {
    const float* C_target = (const float*)d_in[0];
    const float* C        = (const float*)d_in[1];
    const float* X        = (const float*)d_in[2];
    const float* alpha    = (const float*)d_in[3];
    const int*   mask     = (const int*)  d_in[4];
    const float* Wg1      = (const float*)d_in[5];
    const float* Wg2      = (const float*)d_in[6];
    const float* Wg0      = (const float*)d_in[7];
    const float* bias     = (const float*)d_in[8];
    float* out = (float*)d_out;

    char* ws = (char*)d_ws;
    bf16_t* wg1t  = (bf16_t*)(ws);                   // 512 KB
    float*  g     = (float*)(ws + (512u << 10));     // 512 KB
    float*  score = (float*)(ws + (1024u << 10));    // 512 KB
    float*  p     = (float*)(ws + (1536u << 10));    // 512 KB
    float*  part  = (float*)(ws + (2048u << 10));    // 2 MB

    hipMemsetAsync(d_out, 0, (size_t)out_size * sizeof(float), stream);
    k_wg1t  <<<dim3(16, 16), dim3(32, 8), 0, stream>>>(Wg1, wg1t);
    k_gate  <<<dim3(256, 2), 256, 0, stream>>>(C_target, Wg2, bias, g);
    k_score <<<2048, 256, 0, stream>>>(C, wg1t, g, Wg0, mask, score);
    k_entmax<<<256, 64, 0, stream>>>(score, alpha, p);
    k_attn  <<<dim3(256, 4), 256, 0, stream>>>(p, C, part);
    k_out   <<<dim3(256, 4), 256, 0, stream>>>(part, X, out);
}